// Round 5
// baseline (196.348 us; speedup 1.0000x reference)
//
#include <hip/hip_runtime.h>

#define LSIZE 24
#define VOL (LSIZE*LSIZE*LSIZE*LSIZE)       // 331776 sites
#define NLINES (LSIZE*LSIZE*LSIZE)          // 13824 lines per direction
#define TPL 8                               // threads per line (3 matrices each)
#define TPB 256                             // 4 waves, 32 lines per block
#define NTHREADS (4*NLINES*TPL)             // 442368

__device__ __forceinline__ void copy9(float* d, const float* s) {
#pragma unroll
  for (int e = 0; e < 9; ++e) d[e] = s[e];
}
__device__ __forceinline__ void setI9(float* re, float* im) {
#pragma unroll
  for (int e = 0; e < 9; ++e) { re[e] = (e == 0 || e == 4 || e == 8) ? 1.f : 0.f; im[e] = 0.f; }
}

// (o_re,o_im) = a * b, complex 3x3 matmul (row-major)
__device__ __forceinline__ void cmul(const float* ar, const float* ai,
                                     const float* br, const float* bi,
                                     float* or_, float* oi_) {
#pragma unroll
  for (int i = 0; i < 3; ++i) {
#pragma unroll
    for (int j = 0; j < 3; ++j) {
      float sr = 0.f, si = 0.f;
#pragma unroll
      for (int m = 0; m < 3; ++m) {
        float x = ar[i*3+m], y = ai[i*3+m];
        float u = br[m*3+j], v = bi[m*3+j];
        sr = fmaf(x, u, sr);
        sr = fmaf(-y, v, sr);
        si = fmaf(x, v, si);
        si = fmaf(y, u, si);
      }
      or_[i*3+j] = sr;
      oi_[i*3+j] = si;
    }
  }
}

__device__ __forceinline__ void shfl18(float* dr, float* di,
                                       const float* sr, const float* si, int srcLane) {
#pragma unroll
  for (int e = 0; e < 9; ++e) {
    dr[e] = __shfl(sr[e], srcLane, 64);
    di[e] = __shfl(si[e], srcLane, 64);
  }
}

__device__ __forceinline__ void load18(const float* __restrict__ pr,
                                       const float* __restrict__ pi,
                                       float* re, float* im) {
#pragma unroll
  for (int e = 0; e < 9; ++e) { re[e] = pr[e]; im[e] = pi[e]; }
}

// 8 threads per line, all in one wave (lane = j*8 + lineInWave).
// Segment product R_j = U_{3j} U_{3j+1} U_{3j+2}; shuffle-based inclusive
// prefix/suffix scans over the 8 R_j; M_j = SufEx_j * PreEx_j; then
//   P(3j)   = R_j * M_j
//   P(3j+1) = s1_j * M_j * U_{3j}      (s1 = U_{3j+1} U_{3j+2})
//   P(3j+2) = U_{3j+2} * M_j * a1_j    (a1 = U_{3j} U_{3j+1})
__global__ __launch_bounds__(TPB, 2) void polyakov_seg(
    const float* __restrict__ U_re, const float* __restrict__ U_im,
    float* __restrict__ out) {
  int tid = threadIdx.x;
  int lane = tid & 63;
  int wave = tid >> 6;
  int lineInWave = lane & 7;    // fast index -> coalesced global access
  int j = lane >> 3;            // segment index 0..7

  int L = blockIdx.x * 32 + wave * 8 + lineInWave;
  int mu = L / NLINES;
  int l  = L - mu * NLINES;
  int cC = l % LSIZE;
  int cB = (l / LSIZE) % LSIZE;
  int cA = l / (LSIZE*LSIZE);

  int x0, x1, x2, x3, st;
  if (mu == 0)      { x0 = 0;  x1 = cA; x2 = cB; x3 = cC; st = LSIZE*LSIZE*LSIZE; }
  else if (mu == 1) { x0 = cA; x1 = 0;  x2 = cB; x3 = cC; st = LSIZE*LSIZE; }
  else if (mu == 2) { x0 = cA; x1 = cB; x2 = 0;  x3 = cC; st = LSIZE; }
  else              { x0 = cA; x1 = cB; x2 = cC; x3 = 0;  st = 1; }
  int s0 = ((x0*LSIZE + x1)*LSIZE + x2)*LSIZE + x3;

  const float* baseR = U_re + (size_t)mu * (VOL*9);
  const float* baseI = U_im + (size_t)mu * (VOL*9);

  int k0 = 3 * j;
  float U0r[9], U0i[9], U1r[9], U1i[9], U2r[9], U2i[9];
  load18(baseR + (size_t)(s0 + k0*st) * 9,       baseI + (size_t)(s0 + k0*st) * 9,       U0r, U0i);
  load18(baseR + (size_t)(s0 + (k0+1)*st) * 9,   baseI + (size_t)(s0 + (k0+1)*st) * 9,   U1r, U1i);
  load18(baseR + (size_t)(s0 + (k0+2)*st) * 9,   baseI + (size_t)(s0 + (k0+2)*st) * 9,   U2r, U2i);

  float a1r[9], a1i[9], s1r[9], s1i[9], Rr[9], Ri[9];
  cmul(U0r, U0i, U1r, U1i, a1r, a1i);   // a1 = U0*U1
  cmul(U1r, U1i, U2r, U2i, s1r, s1i);   // s1 = U1*U2  (U1 dead after)
  cmul(a1r, a1i, U2r, U2i, Rr, Ri);     // R  = U0*U1*U2

  float Pr_[9], Pi_[9], Br[9], Bi[9], Tr[9], Ti[9];

  // ---- inclusive prefix scan over segments: Pre_j = R_0 ... R_j ----
  copy9(Pr_, Rr); copy9(Pi_, Ri);
#pragma unroll
  for (int d = 1; d < TPL; d <<= 1) {
    bool act = (j >= d);
    int src = act ? (lane - 8*d) : lane;
    shfl18(Br, Bi, Pr_, Pi_, src);
    if (act) {
      cmul(Br, Bi, Pr_, Pi_, Tr, Ti);   // Pre = Pre[j-d] * Pre[j]
      copy9(Pr_, Tr); copy9(Pi_, Ti);
    }
  }
  // exclusive: PreEx_j = Pre_{j-1}, I for j==0
  {
    int src = (j >= 1) ? (lane - 8) : lane;
    shfl18(Br, Bi, Pr_, Pi_, src);
    if (j == 0) setI9(Br, Bi);
    copy9(Pr_, Br); copy9(Pi_, Bi);     // Pr_ now holds PreEx
  }

  // ---- inclusive suffix scan: Suf_j = R_j ... R_7 (seed from R, R dead) ----
  float Sr_[9], Si_[9];
  copy9(Sr_, Rr); copy9(Si_, Ri);
#pragma unroll
  for (int d = 1; d < TPL; d <<= 1) {
    bool act = (j + d < TPL);
    int src = act ? (lane + 8*d) : lane;
    shfl18(Br, Bi, Sr_, Si_, src);
    if (act) {
      cmul(Sr_, Si_, Br, Bi, Tr, Ti);   // Suf = Suf[j] * Suf[j+d]
      copy9(Sr_, Tr); copy9(Si_, Ti);
    }
  }
  // exclusive: SufEx_j = Suf_{j+1}, I for j==7
  {
    int src = (j <= 6) ? (lane + 8) : lane;
    shfl18(Br, Bi, Sr_, Si_, src);
    if (j == 7) setI9(Br, Bi);
    copy9(Sr_, Br); copy9(Si_, Bi);     // Sr_ now holds SufEx
  }

  // M = SufEx * PreEx
  float Mr[9], Mi[9];
  cmul(Sr_, Si_, Pr_, Pi_, Mr, Mi);

  float* outR = out + (size_t)mu * (VOL*9);
  float* outI = out + (size_t)(4 + mu) * (VOL*9);

  // P(3j+2) = U2 * M * a1
  cmul(Mr, Mi, a1r, a1i, Tr, Ti);
  cmul(U2r, U2i, Tr, Ti, Br, Bi);
  {
    size_t o = (size_t)(s0 + (k0+2)*st) * 9;
#pragma unroll
    for (int e = 0; e < 9; ++e) { outR[o+e] = Br[e]; outI[o+e] = Bi[e]; }
  }
  // P(3j+1) = s1 * M * U0
  cmul(Mr, Mi, U0r, U0i, Tr, Ti);
  cmul(s1r, s1i, Tr, Ti, Br, Bi);
  {
    size_t o = (size_t)(s0 + (k0+1)*st) * 9;
#pragma unroll
    for (int e = 0; e < 9; ++e) { outR[o+e] = Br[e]; outI[o+e] = Bi[e]; }
  }
  // P(3j) = R * M = (a1*U2) * M  (recompute R to shorten liveness)
  cmul(a1r, a1i, U2r, U2i, Tr, Ti);
  cmul(Tr, Ti, Mr, Mi, Br, Bi);
  {
    size_t o = (size_t)(s0 + k0*st) * 9;
#pragma unroll
    for (int e = 0; e < 9; ++e) { outR[o+e] = Br[e]; outI[o+e] = Bi[e]; }
  }
}

extern "C" void kernel_launch(void* const* d_in, const int* in_sizes, int n_in,
                              void* d_out, int out_size, void* d_ws, size_t ws_size,
                              hipStream_t stream) {
  const float* U_re = (const float*)d_in[0];
  const float* U_im = (const float*)d_in[1];
  float* out = (float*)d_out;
  int nblocks = NTHREADS / TPB;   // 1728
  hipLaunchKernelGGL(polyakov_seg, dim3(nblocks), dim3(TPB), 0, stream, U_re, U_im, out);
}